// Round 1
// baseline (8659.494 us; speedup 1.0000x reference)
//
#include <hip/hip_runtime.h>
#include <cmath>

#define HID 150
#define FOURH 600
#define BATCH 64
#define TLEN 2048

__device__ __forceinline__ float sigmoidf_(float x) {
    return 1.0f / (1.0f + __expf(-x));
}
__device__ __forceinline__ float tanhf_(float x) {
    // tanh(x) = 1 - 2/(exp(2x)+1); correct limits for |x| large, no branches
    return 1.0f - 2.0f / (__expf(2.0f * x) + 1.0f);
}

// x_proj[b, i, c] = bias[c] + sum_k X[b, t0+i, k] * Wx[k, c]
// X rows are contiguous length-150; one block does 32 rows of one batch.
__global__ __launch_bounds__(640, 2) void xproj_gemm(
    const float* __restrict__ X,     // [BATCH, TLEN, 150]
    const float* __restrict__ Wx,    // [150, 600] row-major
    const float* __restrict__ bias,  // [600]
    float* __restrict__ xp,          // [BATCH, C, 600]
    int t0, int C)
{
    const int blocks_per_batch = C / 32;
    const int b  = blockIdx.x / blocks_per_batch;
    const int i0 = (blockIdx.x % blocks_per_batch) * 32;
    const float* Xbase = X + ((size_t)(b * TLEN + t0 + i0)) * HID;

    __shared__ __align__(16) float xt[150 * 36];  // [k][r], padded row=36 for b128 align
    const int tid = threadIdx.x;
    for (int i = tid; i < 32 * HID; i += 640) {
        int r = i / HID, k = i % HID;
        xt[k * 36 + r] = Xbase[(size_t)r * HID + k];
    }
    __syncthreads();

    if (tid < FOURH) {
        float acc[32];
        #pragma unroll
        for (int r = 0; r < 32; ++r) acc[r] = 0.f;
        for (int k = 0; k < HID; ++k) {
            float w = Wx[(size_t)k * FOURH + tid];
            #pragma unroll
            for (int r4 = 0; r4 < 8; ++r4) {
                float4 xv = *(const float4*)&xt[k * 36 + r4 * 4];
                acc[r4*4+0] += xv.x * w;
                acc[r4*4+1] += xv.y * w;
                acc[r4*4+2] += xv.z * w;
                acc[r4*4+3] += xv.w * w;
            }
        }
        float bv = bias[tid];
        float* o = xp + ((size_t)b * C + i0) * FOURH + tid;
        #pragma unroll
        for (int r = 0; r < 32; ++r) o[(size_t)r * FOURH] = acc[r] + bv;
    }
}

// One workgroup per batch element. Thread c (<600) owns Wh[:,c] in registers.
// h lives in LDS (broadcast float4 reads); gates routed through LDS; c-state
// lives in registers of threads 0..149.
__global__ __launch_bounds__(640, 3) void lstm_recur(
    const float* __restrict__ xp,    // [BATCH, C, 600], bias pre-added
    const float* __restrict__ Wh,    // [150, 600]
    float* __restrict__ out,         // [BATCH, TLEN, 150]
    float* __restrict__ state,       // [BATCH, 300]: c then h
    int t0, int C)
{
    const int b = blockIdx.x;
    const int tid = threadIdx.x;
    __shared__ __align__(16) float h_lds[152];
    __shared__ __align__(16) float zact[600];

    float whreg[152];
    float cst = 0.f;
    if (tid < FOURH) {
        #pragma unroll
        for (int k = 0; k < HID; ++k) whreg[k] = Wh[(size_t)k * FOURH + tid];
        whreg[150] = 0.f;
        whreg[151] = 0.f;
    }
    if (tid < 152) {
        float hv = 0.f;
        if (t0 != 0 && tid < HID) hv = state[b * 300 + HID + tid];
        h_lds[tid] = hv;
        if (t0 != 0 && tid < HID) cst = state[b * 300 + tid];
    }
    __syncthreads();

    const float* xpb = xp + (size_t)b * C * FOURH;
    float* outb = out + ((size_t)b * TLEN + t0) * HID;

    float xp_next = (tid < FOURH) ? xpb[tid] : 0.f;

    for (int i = 0; i < C; ++i) {
        float acc = xp_next;
        // prefetch next step's x-projection (hides HBM latency under the dot)
        if (tid < FOURH && i + 1 < C) xp_next = xpb[(size_t)(i + 1) * FOURH + tid];

        if (tid < FOURH) {
            float a0 = 0.f, a1 = 0.f, a2 = 0.f, a3 = 0.f;
            #pragma unroll
            for (int k4 = 0; k4 < 38; ++k4) {
                float4 hv = *(const float4*)&h_lds[k4 * 4];
                a0 += hv.x * whreg[k4*4+0];
                a1 += hv.y * whreg[k4*4+1];
                a2 += hv.z * whreg[k4*4+2];
                a3 += hv.w * whreg[k4*4+3];
            }
            acc += (a0 + a1) + (a2 + a3);
            float a;
            if (tid < 300 || tid >= 450) a = sigmoidf_(acc);  // i, f, o gates
            else                          a = tanhf_(acc);    // g gate
            zact[tid] = a;
        }
        __syncthreads();

        if (tid < HID) {
            float ig = zact[tid];
            float fg = zact[HID + tid];
            float gg = zact[2 * HID + tid];
            float og = zact[3 * HID + tid];
            cst = fg * cst + ig * gg;
            float hn = og * tanhf_(cst);
            h_lds[tid] = hn;
            outb[(size_t)i * HID + tid] = hn;
        }
        __syncthreads();
    }

    if (tid < HID) {
        state[b * 300 + tid] = cst;
        state[b * 300 + HID + tid] = h_lds[tid];
    }
}

extern "C" void kernel_launch(void* const* d_in, const int* in_sizes, int n_in,
                              void* d_out, int out_size, void* d_ws, size_t ws_size,
                              hipStream_t stream) {
    const float* xs  = (const float*)d_in[0];
    const float* Wx0 = (const float*)d_in[1];
    const float* Wh0 = (const float*)d_in[2];
    const float* b0  = (const float*)d_in[3];
    const float* Wx1 = (const float*)d_in[4];
    const float* Wh1 = (const float*)d_in[5];
    const float* b1  = (const float*)d_in[6];
    float* out = (float*)d_out;

    // Pick the largest time-chunk whose x_proj buffer fits in the workspace.
    int C = TLEN;
    while (C > 32) {
        size_t need = (size_t)BATCH * C * FOURH * sizeof(float) + (size_t)BATCH * 300 * sizeof(float);
        if (need <= ws_size) break;
        C >>= 1;
    }
    float* xp = (float*)d_ws;
    float* state = (float*)d_ws + (size_t)BATCH * C * FOURH;

    const int nchunk = TLEN / C;
    for (int layer = 0; layer < 2; ++layer) {
        const float* X    = (layer == 0) ? xs  : out;   // layer 1 reads layer-0 output
        const float* Wx   = (layer == 0) ? Wx0 : Wx1;
        const float* Wh   = (layer == 0) ? Wh0 : Wh1;
        const float* bias = (layer == 0) ? b0  : b1;
        for (int ch = 0; ch < nchunk; ++ch) {
            int t0 = ch * C;
            xproj_gemm<<<dim3(BATCH * (C / 32)), dim3(640), 0, stream>>>(X, Wx, bias, xp, t0, C);
            lstm_recur<<<dim3(BATCH), dim3(640), 0, stream>>>(xp, Wh, out, state, t0, C);
        }
    }
}

// Round 2
// 4834.288 us; speedup vs baseline: 1.7913x; 1.7913x over previous
//
#include <hip/hip_runtime.h>
#include <cmath>

#define HID 150
#define FOURH 600
#define BATCH 64
#define TLEN 2048

__device__ __forceinline__ float sigmoidf_(float x) {
    return 1.0f / (1.0f + __expf(-x));
}
__device__ __forceinline__ float tanhf_(float x) {
    // tanh(x) = 1 - 2/(exp(2x)+1); correct limits for |x| large, no branches
    return 1.0f - 2.0f / (__expf(2.0f * x) + 1.0f);
}

// x_proj[b, i, c] = bias[c] + sum_k X[b, t0+i, k] * Wx[k, c]
__global__ __launch_bounds__(640, 2) void xproj_gemm(
    const float* __restrict__ X,     // [BATCH, TLEN, 150]
    const float* __restrict__ Wx,    // [150, 600] row-major
    const float* __restrict__ bias,  // [600]
    float* __restrict__ xp,          // [BATCH, C, 600]
    int t0, int C)
{
    const int blocks_per_batch = C / 32;
    const int b  = blockIdx.x / blocks_per_batch;
    const int i0 = (blockIdx.x % blocks_per_batch) * 32;
    const float* Xbase = X + ((size_t)(b * TLEN + t0 + i0)) * HID;

    __shared__ __align__(16) float xt[150 * 36];  // [k][r], padded row=36
    const int tid = threadIdx.x;
    for (int i = tid; i < 32 * HID; i += 640) {
        int r = i / HID, k = i % HID;
        xt[k * 36 + r] = Xbase[(size_t)r * HID + k];
    }
    __syncthreads();

    if (tid < FOURH) {
        float acc[32];
        #pragma unroll
        for (int r = 0; r < 32; ++r) acc[r] = 0.f;
        for (int k = 0; k < HID; ++k) {
            float w = Wx[(size_t)k * FOURH + tid];
            #pragma unroll
            for (int r4 = 0; r4 < 8; ++r4) {
                float4 xv = *(const float4*)&xt[k * 36 + r4 * 4];
                acc[r4*4+0] += xv.x * w;
                acc[r4*4+1] += xv.y * w;
                acc[r4*4+2] += xv.z * w;
                acc[r4*4+3] += xv.w * w;
            }
        }
        float bv = bias[tid];
        float* o = xp + ((size_t)b * C + i0) * FOURH + tid;
        #pragma unroll
        for (int r = 0; r < 32; ++r) o[(size_t)r * FOURH] = acc[r] + bv;
    }
}

// One workgroup per batch element, 768 threads (12 waves, exactly 3/SIMD ->
// VGPR cap 170). Thread (j, ks): j = unit index (0..149), ks = k-slice
// (0..4, 32-wide over k padded to 160). Owns w[4][32] = 128 weight VGPRs --
// all 4 gates of unit j over its k-slice. h lives in LDS (wave-uniform
// broadcast float4 reads). Partials reduced via part[ks][g][j] (consecutive-j
// lanes => conflict-free).
__global__ __launch_bounds__(768, 3) void lstm_recur(
    const float* __restrict__ xp,    // [BATCH, C, 600], bias pre-added
    const float* __restrict__ Wh,    // [150, 600]
    float* __restrict__ out,         // [BATCH, TLEN, 150]
    float* __restrict__ state,       // [BATCH, 300]: c then h
    int t0, int C)
{
    const int b = blockIdx.x;
    const int tid = threadIdx.x;
    const int ks = tid / HID;        // 0..4 for tid < 750
    const int j  = tid - ks * HID;   // 0..149

    __shared__ __align__(16) float h_pad[160];       // k padded 150->160, tail zero
    __shared__ __align__(16) float part[5][4][152];  // [ks][g][j]

    // Per-thread weights: w[g][kk] = Wh[32*ks+kk][g*150+j], zero for k>=150.
    float w[4][32];
    if (tid < 750) {
        #pragma unroll
        for (int g = 0; g < 4; ++g) {
            #pragma unroll
            for (int kk = 0; kk < 32; ++kk) {
                int k = ks * 32 + kk;
                w[g][kk] = (k < HID) ? Wh[(size_t)k * FOURH + g * HID + j] : 0.f;
            }
        }
    }

    float cst = 0.f;
    if (tid < 160) h_pad[tid] = 0.f;
    if (t0 != 0 && tid < HID) {
        cst = state[b * 300 + tid];
        h_pad[tid] = state[b * 300 + HID + tid];
    }
    __syncthreads();

    const float* xpb = xp + (size_t)b * C * FOURH;
    float* outb = out + ((size_t)b * TLEN + t0) * HID;

    // Prefetched x-projection for step 0 (threads 0..149 hold all 4 gates).
    float xn0 = 0.f, xn1 = 0.f, xn2 = 0.f, xn3 = 0.f;
    if (tid < HID) {
        xn0 = xpb[tid];
        xn1 = xpb[HID + tid];
        xn2 = xpb[2 * HID + tid];
        xn3 = xpb[3 * HID + tid];
    }

    for (int i = 0; i < C; ++i) {
        // ---- Stage A: partial dots (750 threads, 128 FMA each) ----
        if (tid < 750) {
            float a0 = 0.f, a1 = 0.f, a2 = 0.f, a3 = 0.f;
            #pragma unroll
            for (int kk = 0; kk < 8; ++kk) {
                float4 hv = *(const float4*)&h_pad[ks * 32 + kk * 4];
                a0 += hv.x * w[0][kk*4+0]; a0 += hv.y * w[0][kk*4+1];
                a0 += hv.z * w[0][kk*4+2]; a0 += hv.w * w[0][kk*4+3];
                a1 += hv.x * w[1][kk*4+0]; a1 += hv.y * w[1][kk*4+1];
                a1 += hv.z * w[1][kk*4+2]; a1 += hv.w * w[1][kk*4+3];
                a2 += hv.x * w[2][kk*4+0]; a2 += hv.y * w[2][kk*4+1];
                a2 += hv.z * w[2][kk*4+2]; a2 += hv.w * w[2][kk*4+3];
                a3 += hv.x * w[3][kk*4+0]; a3 += hv.y * w[3][kk*4+1];
                a3 += hv.z * w[3][kk*4+2]; a3 += hv.w * w[3][kk*4+3];
            }
            part[ks][0][j] = a0;
            part[ks][1][j] = a1;
            part[ks][2][j] = a2;
            part[ks][3][j] = a3;
        }
        __syncthreads();

        // ---- Stage B: reduce 5 partials/gate, activate, update c/h (150 thr) ----
        if (tid < HID) {
            // issue next step's xp prefetch first (hides HBM under the rest)
            float p0 = xn0, p1 = xn1, p2 = xn2, p3 = xn3;
            if (i + 1 < C) {
                const float* p = &xpb[(size_t)(i + 1) * FOURH];
                xn0 = p[tid];
                xn1 = p[HID + tid];
                xn2 = p[2 * HID + tid];
                xn3 = p[3 * HID + tid];
            }
            float z0 = p0, z1 = p1, z2 = p2, z3 = p3;
            #pragma unroll
            for (int s = 0; s < 5; ++s) {
                z0 += part[s][0][tid];
                z1 += part[s][1][tid];
                z2 += part[s][2][tid];
                z3 += part[s][3][tid];
            }
            float ig = sigmoidf_(z0);
            float fg = sigmoidf_(z1);
            float gg = tanhf_(z2);
            float og = sigmoidf_(z3);
            cst = fg * cst + ig * gg;
            float hn = og * tanhf_(cst);
            h_pad[tid] = hn;
            outb[(size_t)i * HID + tid] = hn;
        }
        __syncthreads();
    }

    if (tid < HID) {
        state[b * 300 + tid] = cst;
        state[b * 300 + HID + tid] = h_pad[tid];
    }
}

extern "C" void kernel_launch(void* const* d_in, const int* in_sizes, int n_in,
                              void* d_out, int out_size, void* d_ws, size_t ws_size,
                              hipStream_t stream) {
    const float* xs  = (const float*)d_in[0];
    const float* Wx0 = (const float*)d_in[1];
    const float* Wh0 = (const float*)d_in[2];
    const float* b0  = (const float*)d_in[3];
    const float* Wx1 = (const float*)d_in[4];
    const float* Wh1 = (const float*)d_in[5];
    const float* b1  = (const float*)d_in[6];
    float* out = (float*)d_out;

    // Pick the largest time-chunk whose x_proj buffer fits in the workspace.
    int C = TLEN;
    while (C > 32) {
        size_t need = (size_t)BATCH * C * FOURH * sizeof(float) + (size_t)BATCH * 300 * sizeof(float);
        if (need <= ws_size) break;
        C >>= 1;
    }
    float* xp = (float*)d_ws;
    float* state = (float*)d_ws + (size_t)BATCH * C * FOURH;

    const int nchunk = TLEN / C;
    for (int layer = 0; layer < 2; ++layer) {
        const float* X    = (layer == 0) ? xs  : out;   // layer 1 reads layer-0 output
        const float* Wx   = (layer == 0) ? Wx0 : Wx1;
        const float* Wh   = (layer == 0) ? Wh0 : Wh1;
        const float* bias = (layer == 0) ? b0  : b1;
        for (int ch = 0; ch < nchunk; ++ch) {
            int t0 = ch * C;
            xproj_gemm<<<dim3(BATCH * (C / 32)), dim3(640), 0, stream>>>(X, Wx, bias, xp, t0, C);
            lstm_recur<<<dim3(BATCH), dim3(768), 0, stream>>>(xp, Wh, out, state, t0, C);
        }
    }
}

// Round 3
// 4783.447 us; speedup vs baseline: 1.8103x; 1.0106x over previous
//
#include <hip/hip_runtime.h>
#include <cmath>

#define HID 150
#define FOURH 600
#define BATCH 64
#define TLEN 2048

__device__ __forceinline__ float sigmoidf_(float x) {
    return 1.0f / (1.0f + __expf(-x));
}
__device__ __forceinline__ float tanhf_(float x) {
    // tanh(x) = 1 - 2/(exp(2x)+1); correct limits for |x| large, no branches
    return 1.0f - 2.0f / (__expf(2.0f * x) + 1.0f);
}

// x_proj[b, i, c] = bias[c] + sum_k X[b, t0+i, k] * Wx[k, c]
__global__ __launch_bounds__(640, 2) void xproj_gemm(
    const float* __restrict__ X,     // [BATCH, TLEN, 150]
    const float* __restrict__ Wx,    // [150, 600] row-major
    const float* __restrict__ bias,  // [600]
    float* __restrict__ xp,          // [BATCH, C, 600]
    int t0, int C)
{
    const int blocks_per_batch = C / 32;
    const int b  = blockIdx.x / blocks_per_batch;
    const int i0 = (blockIdx.x % blocks_per_batch) * 32;
    const float* Xbase = X + ((size_t)(b * TLEN + t0 + i0)) * HID;

    __shared__ __align__(16) float xt[150 * 36];  // [k][r], padded row=36
    const int tid = threadIdx.x;
    for (int i = tid; i < 32 * HID; i += 640) {
        int r = i / HID, k = i % HID;
        xt[k * 36 + r] = Xbase[(size_t)r * HID + k];
    }
    __syncthreads();

    if (tid < FOURH) {
        float acc[32];
        #pragma unroll
        for (int r = 0; r < 32; ++r) acc[r] = 0.f;
        for (int k = 0; k < HID; ++k) {
            float w = Wx[(size_t)k * FOURH + tid];
            #pragma unroll
            for (int r4 = 0; r4 < 8; ++r4) {
                float4 xv = *(const float4*)&xt[k * 36 + r4 * 4];
                acc[r4*4+0] += xv.x * w;
                acc[r4*4+1] += xv.y * w;
                acc[r4*4+2] += xv.z * w;
                acc[r4*4+3] += xv.w * w;
            }
        }
        float bv = bias[tid];
        float* o = xp + ((size_t)b * C + i0) * FOURH + tid;
        #pragma unroll
        for (int r = 0; r < 32; ++r) o[(size_t)r * FOURH] = acc[r] + bv;
    }
}

// ---- literal-index weight access machinery (defeats SROA failure/spill) ----
// Load one element: arr[K] = (kbase+K < 150) ? Whj[K*600] : 0
#define LDI(arr, K) arr[(K)] = (kbase + (K) < HID) ? Whj[(size_t)(K) * FOURH] : 0.f;
#define LDI4(arr, B) LDI(arr,(B)+0) LDI(arr,(B)+1) LDI(arr,(B)+2) LDI(arr,(B)+3)
#define LDI32(arr) LDI4(arr,0) LDI4(arr,4) LDI4(arr,8) LDI4(arr,12) \
                   LDI4(arr,16) LDI4(arr,20) LDI4(arr,24) LDI4(arr,28)
#define LDGATE(arr, goff) { const float* Whj = Wh + (size_t)kbase * FOURH + (goff) + j; LDI32(arr) }

// One FMA block over 4 consecutive k values (B is a literal multiple of 4)
#define FMB(B) { float4 hv = *(const float4*)&h_pad[kbase + (B)]; \
  a0 += hv.x*w0[(B)+0]; a0 += hv.y*w0[(B)+1]; a0 += hv.z*w0[(B)+2]; a0 += hv.w*w0[(B)+3]; \
  a1 += hv.x*w1[(B)+0]; a1 += hv.y*w1[(B)+1]; a1 += hv.z*w1[(B)+2]; a1 += hv.w*w1[(B)+3]; \
  a2 += hv.x*w2[(B)+0]; a2 += hv.y*w2[(B)+1]; a2 += hv.z*w2[(B)+2]; a2 += hv.w*w2[(B)+3]; \
  a3 += hv.x*w3[(B)+0]; a3 += hv.y*w3[(B)+1]; a3 += hv.z*w3[(B)+2]; a3 += hv.w*w3[(B)+3]; }

// One workgroup per batch element, 768 threads (12 waves = 3/SIMD, pinned via
// amdgpu_waves_per_eu(3,3) -> VGPR budget 170, no incentive to spill).
// Thread (j, ks): j = unit (0..149), ks = 32-wide k-slice (0..4, k padded to
// 160). Owns 4x32 = 128 weight scalars (all 4 gates of unit j, its k-slice).
__global__ __launch_bounds__(768) __attribute__((amdgpu_waves_per_eu(3, 3)))
void lstm_recur(
    const float* __restrict__ xp,    // [BATCH, C, 600], bias pre-added
    const float* __restrict__ Wh,    // [150, 600]
    float* __restrict__ out,         // [BATCH, TLEN, 150]
    float* __restrict__ state,       // [BATCH, 300]: c then h
    int t0, int C)
{
    const int b = blockIdx.x;
    const int tid = threadIdx.x;
    const int ks = tid / HID;        // 0..4 for tid < 750
    const int j  = tid - ks * HID;   // 0..149
    const int kbase = ks * 32;

    __shared__ __align__(16) float h_pad[160];       // k padded 150->160, tail stays zero
    __shared__ __align__(16) float part[5][4][152];  // [ks][g][j]

    float w0[32], w1[32], w2[32], w3[32];
    if (tid < 750) {
        LDGATE(w0, 0)
        LDGATE(w1, HID)
        LDGATE(w2, 2 * HID)
        LDGATE(w3, 3 * HID)
    }

    float cst = 0.f;
    if (tid < 160) h_pad[tid] = 0.f;
    if (t0 != 0 && tid < HID) {
        cst = state[b * 300 + tid];
        h_pad[tid] = state[b * 300 + HID + tid];
    }
    __syncthreads();

    const float* xpb = xp + (size_t)b * C * FOURH;
    float* outb = out + ((size_t)b * TLEN + t0) * HID;

    // Prefetched x-projection for step 0 (threads 0..149 hold all 4 gates).
    float xn0 = 0.f, xn1 = 0.f, xn2 = 0.f, xn3 = 0.f;
    if (tid < HID) {
        xn0 = xpb[tid];
        xn1 = xpb[HID + tid];
        xn2 = xpb[2 * HID + tid];
        xn3 = xpb[3 * HID + tid];
    }

    for (int i = 0; i < C; ++i) {
        // ---- Stage A: partial dots (750 threads, 128 FMA each, all literal-indexed) ----
        if (tid < 750) {
            float a0 = 0.f, a1 = 0.f, a2 = 0.f, a3 = 0.f;
            FMB(0) FMB(4) FMB(8) FMB(12) FMB(16) FMB(20) FMB(24) FMB(28)
            part[ks][0][j] = a0;
            part[ks][1][j] = a1;
            part[ks][2][j] = a2;
            part[ks][3][j] = a3;
        }
        __syncthreads();

        // ---- Stage B: reduce 5 partials/gate, activate, update c/h (150 thr) ----
        if (tid < HID) {
            // issue next step's xp prefetch first (hides HBM/L2 under the rest)
            float p0 = xn0, p1 = xn1, p2 = xn2, p3 = xn3;
            if (i + 1 < C) {
                const float* p = &xpb[(size_t)(i + 1) * FOURH];
                xn0 = p[tid];
                xn1 = p[HID + tid];
                xn2 = p[2 * HID + tid];
                xn3 = p[3 * HID + tid];
            }
            float z0 = p0, z1 = p1, z2 = p2, z3 = p3;
            #pragma unroll
            for (int s = 0; s < 5; ++s) {
                z0 += part[s][0][tid];
                z1 += part[s][1][tid];
                z2 += part[s][2][tid];
                z3 += part[s][3][tid];
            }
            float ig = sigmoidf_(z0);
            float fg = sigmoidf_(z1);
            float gg = tanhf_(z2);
            float og = sigmoidf_(z3);
            cst = fg * cst + ig * gg;
            float hn = og * tanhf_(cst);
            h_pad[tid] = hn;
            outb[(size_t)i * HID + tid] = hn;
        }
        __syncthreads();
    }

    if (tid < HID) {
        state[b * 300 + tid] = cst;
        state[b * 300 + HID + tid] = h_pad[tid];
    }
}

extern "C" void kernel_launch(void* const* d_in, const int* in_sizes, int n_in,
                              void* d_out, int out_size, void* d_ws, size_t ws_size,
                              hipStream_t stream) {
    const float* xs  = (const float*)d_in[0];
    const float* Wx0 = (const float*)d_in[1];
    const float* Wh0 = (const float*)d_in[2];
    const float* b0  = (const float*)d_in[3];
    const float* Wx1 = (const float*)d_in[4];
    const float* Wh1 = (const float*)d_in[5];
    const float* b1  = (const float*)d_in[6];
    float* out = (float*)d_out;

    // Pick the largest time-chunk whose x_proj buffer fits in the workspace.
    int C = TLEN;
    while (C > 32) {
        size_t need = (size_t)BATCH * C * FOURH * sizeof(float) + (size_t)BATCH * 300 * sizeof(float);
        if (need <= ws_size) break;
        C >>= 1;
    }
    float* xp = (float*)d_ws;
    float* state = (float*)d_ws + (size_t)BATCH * C * FOURH;

    const int nchunk = TLEN / C;
    for (int layer = 0; layer < 2; ++layer) {
        const float* X    = (layer == 0) ? xs  : out;   // layer 1 reads layer-0 output
        const float* Wx   = (layer == 0) ? Wx0 : Wx1;
        const float* Wh   = (layer == 0) ? Wh0 : Wh1;
        const float* bias = (layer == 0) ? b0  : b1;
        for (int ch = 0; ch < nchunk; ++ch) {
            int t0 = ch * C;
            xproj_gemm<<<dim3(BATCH * (C / 32)), dim3(640), 0, stream>>>(X, Wx, bias, xp, t0, C);
            lstm_recur<<<dim3(BATCH), dim3(768), 0, stream>>>(xp, Wh, out, state, t0, C);
        }
    }
}

// Round 4
// 2990.591 us; speedup vs baseline: 2.8956x; 1.5995x over previous
//
#include <hip/hip_runtime.h>
#include <cmath>

#define HID 150
#define FOURH 600
#define BATCH 64
#define TLEN 2048
#define NKS 5  // 32-wide k-slices over k padded 150->160

typedef __attribute__((ext_vector_type(2))) _Float16 half2_t;

#if defined(__has_builtin)
#if __has_builtin(__builtin_amdgcn_fdot2)
#define FDOT2(a, b, c) __builtin_amdgcn_fdot2((a), (b), (c), false)
#endif
#endif
#ifndef FDOT2
__device__ __forceinline__ float fdot2_fb(half2_t a, half2_t b, float c) {
    return c + (float)a.x * (float)b.x + (float)a.y * (float)b.y;
}
#define FDOT2(a, b, c) fdot2_fb((a), (b), (c))
#endif

__device__ __forceinline__ float sigmoidf_(float x) {
    return 1.0f / (1.0f + __expf(-x));
}
__device__ __forceinline__ float tanhf_(float x) {
    return 1.0f - 2.0f / (__expf(2.0f * x) + 1.0f);
}

// x_proj[b, i, c] = bias[c] + sum_k X[b, t0+i, k] * Wx[k, c]   (f32)
__global__ __launch_bounds__(640, 2) void xproj_gemm(
    const float* __restrict__ X,     // [BATCH, TLEN, 150]
    const float* __restrict__ Wx,    // [150, 600]
    const float* __restrict__ bias,  // [600]
    float* __restrict__ xp,          // [BATCH, C, 600]
    int t0, int C)
{
    const int blocks_per_batch = C / 32;
    const int b  = blockIdx.x / blocks_per_batch;
    const int i0 = (blockIdx.x % blocks_per_batch) * 32;
    const float* Xbase = X + ((size_t)(b * TLEN + t0 + i0)) * HID;

    __shared__ __align__(16) float xt[150 * 36];
    const int tid = threadIdx.x;
    for (int i = tid; i < 32 * HID; i += 640) {
        int r = i / HID, k = i % HID;
        xt[k * 36 + r] = Xbase[(size_t)r * HID + k];
    }
    __syncthreads();

    if (tid < FOURH) {
        float acc[32];
        #pragma unroll
        for (int r = 0; r < 32; ++r) acc[r] = 0.f;
        for (int k = 0; k < HID; ++k) {
            float w = Wx[(size_t)k * FOURH + tid];
            #pragma unroll
            for (int r4 = 0; r4 < 8; ++r4) {
                float4 xv = *(const float4*)&xt[k * 36 + r4 * 4];
                acc[r4*4+0] += xv.x * w;
                acc[r4*4+1] += xv.y * w;
                acc[r4*4+2] += xv.z * w;
                acc[r4*4+3] += xv.w * w;
            }
        }
        float bv = bias[tid];
        float* o = xp + ((size_t)b * C + i0) * FOURH + tid;
        #pragma unroll
        for (int r = 0; r < 32; ++r) o[(size_t)r * FOURH] = acc[r] + bv;
    }
}

// Pack Wh (f32 [150,600]) into per-thread-sliced half2 layout:
// whp[layer][ks*9600 + (g*16+p)*150 + j] = (Wh[32ks+2p][g*150+j], Wh[32ks+2p+1][...])
__global__ void pack_wh(const float* __restrict__ Wh0, const float* __restrict__ Wh1,
                        half2_t* __restrict__ whp) {
    int idx = blockIdx.x * 256 + threadIdx.x;
    if (idx >= 2 * 48000) return;
    int layer = idx / 48000, r = idx - layer * 48000;
    int j = r % HID, t = r / HID;       // t = (ks*4+g)*16+p
    int p = t & 15, gks = t >> 4;
    int g = gks & 3, ks = gks >> 2;
    const float* Wh = layer ? Wh1 : Wh0;
    int k0 = ks * 32 + 2 * p;
    float a  = (k0 < HID)     ? Wh[(size_t)k0 * FOURH + g * HID + j]       : 0.f;
    float bb = (k0 + 1 < HID) ? Wh[(size_t)(k0 + 1) * FOURH + g * HID + j] : 0.f;
    half2_t h; h.x = (_Float16)a; h.y = (_Float16)bb;
    whp[idx] = h;
}

// ---- literal-index weight machinery ----
#define WL(arr, G, P) arr[(P)] = Wj[((G) * 16 + (P)) * HID];
#define WL16(arr, G) WL(arr,G,0) WL(arr,G,1) WL(arr,G,2) WL(arr,G,3) WL(arr,G,4) \
  WL(arr,G,5) WL(arr,G,6) WL(arr,G,7) WL(arr,G,8) WL(arr,G,9) WL(arr,G,10) \
  WL(arr,G,11) WL(arr,G,12) WL(arr,G,13) WL(arr,G,14) WL(arr,G,15)

// One quarter of the k-slice: 4 half2 of h (16B LDS read), 16 fdot2.
#define DOTQ(Q) { \
  float4 hv = *(const float4*)(const void*)&h16[ks * 32 + (Q) * 8]; \
  half2_t h0 = __builtin_bit_cast(half2_t, hv.x); \
  half2_t h1 = __builtin_bit_cast(half2_t, hv.y); \
  half2_t h2 = __builtin_bit_cast(half2_t, hv.z); \
  half2_t h3 = __builtin_bit_cast(half2_t, hv.w); \
  a0 = FDOT2(h0, w0[(Q)*4+0], a0); a0 = FDOT2(h1, w0[(Q)*4+1], a0); \
  a0 = FDOT2(h2, w0[(Q)*4+2], a0); a0 = FDOT2(h3, w0[(Q)*4+3], a0); \
  a1 = FDOT2(h0, w1[(Q)*4+0], a1); a1 = FDOT2(h1, w1[(Q)*4+1], a1); \
  a1 = FDOT2(h2, w1[(Q)*4+2], a1); a1 = FDOT2(h3, w1[(Q)*4+3], a1); \
  a2 = FDOT2(h0, w2[(Q)*4+0], a2); a2 = FDOT2(h1, w2[(Q)*4+1], a2); \
  a2 = FDOT2(h2, w2[(Q)*4+2], a2); a2 = FDOT2(h3, w2[(Q)*4+3], a2); \
  a3 = FDOT2(h0, w3[(Q)*4+0], a3); a3 = FDOT2(h1, w3[(Q)*4+1], a3); \
  a3 = FDOT2(h2, w3[(Q)*4+2], a3); a3 = FDOT2(h3, w3[(Q)*4+3], a3); }

// Dual-part recurrence: WGs 0-63 = part A (layer L, chunk s), WGs 64-127 =
// part B (other layer, chunk s-1). 768 threads; thread (j, ks) owns all 4
// gates of unit j over a 32-wide k-slice as 64 packed half2 registers.
__global__ __launch_bounds__(768)
__attribute__((amdgpu_waves_per_eu(3, 4)))
void lstm_recur2(const float* __restrict__ xpA, const half2_t* __restrict__ whpA,
                 float* __restrict__ stA, int t0A,
                 const float* __restrict__ xpB, const half2_t* __restrict__ whpB,
                 float* __restrict__ stB, int t0B,
                 float* __restrict__ out, int C)
{
    const int part = blockIdx.x >> 6;
    const int b = blockIdx.x & 63;
    const int tid = threadIdx.x;
    const int ks = tid / HID;        // 0..4 for tid < 750
    const int j  = tid - ks * HID;   // 0..149

    const float*   xp    = part ? xpB  : xpA;
    const half2_t* whp   = part ? whpB : whpA;
    float*         state = part ? stB  : stA;
    const int      t0    = part ? t0B  : t0A;

    __shared__ __align__(16) _Float16 h16[160];      // h as f16, tail zero
    __shared__ __align__(16) float part_s[NKS][4][152];

    half2_t w0[16], w1[16], w2[16], w3[16];
    if (tid < 750) {
        const half2_t* Wj = whp + (size_t)ks * 9600 + j;
        WL16(w0, 0) WL16(w1, 1) WL16(w2, 2) WL16(w3, 3)
    }

    float cst = 0.f;
    if (tid < 160) {
        float hv = 0.f;
        if (t0 != 0 && tid < HID) {
            cst = state[b * 300 + tid];
            hv  = state[b * 300 + HID + tid];
        }
        h16[tid] = (_Float16)hv;
    }
    __syncthreads();

    const float* xpb = xp + (size_t)b * C * FOURH;
    float* outb = out + ((size_t)b * TLEN + t0) * HID;

    float xn0 = 0.f, xn1 = 0.f, xn2 = 0.f, xn3 = 0.f;
    if (tid < HID) {
        xn0 = xpb[tid];
        xn1 = xpb[HID + tid];
        xn2 = xpb[2 * HID + tid];
        xn3 = xpb[3 * HID + tid];
    }

    for (int i = 0; i < C; ++i) {
        // ---- Stage A: 64 v_dot2 per thread (750 threads) ----
        if (tid < 750) {
            float a0 = 0.f, a1 = 0.f, a2 = 0.f, a3 = 0.f;
            DOTQ(0) DOTQ(1) DOTQ(2) DOTQ(3)
            part_s[ks][0][j] = a0;
            part_s[ks][1][j] = a1;
            part_s[ks][2][j] = a2;
            part_s[ks][3][j] = a3;
        }
        __syncthreads();

        // ---- Stage B: reduce, activate, update c/h (150 threads) ----
        if (tid < HID) {
            float p0 = xn0, p1 = xn1, p2 = xn2, p3 = xn3;
            if (i + 1 < C) {
                const float* p = &xpb[(size_t)(i + 1) * FOURH];
                xn0 = p[tid];
                xn1 = p[HID + tid];
                xn2 = p[2 * HID + tid];
                xn3 = p[3 * HID + tid];
            }
            float z0 = p0, z1 = p1, z2 = p2, z3 = p3;
            #pragma unroll
            for (int s = 0; s < NKS; ++s) {
                z0 += part_s[s][0][tid];
                z1 += part_s[s][1][tid];
                z2 += part_s[s][2][tid];
                z3 += part_s[s][3][tid];
            }
            float ig = sigmoidf_(z0);
            float fg = sigmoidf_(z1);
            float gg = tanhf_(z2);
            float og = sigmoidf_(z3);
            cst = fg * cst + ig * gg;
            float hn = og * tanhf_(cst);
            h16[tid] = (_Float16)hn;
            outb[(size_t)i * HID + tid] = hn;
        }
        __syncthreads();
    }

    if (tid < HID) {
        state[b * 300 + tid] = cst;
        state[b * 300 + HID + tid] = (float)h16[tid];
    }
}

extern "C" void kernel_launch(void* const* d_in, const int* in_sizes, int n_in,
                              void* d_out, int out_size, void* d_ws, size_t ws_size,
                              hipStream_t stream) {
    const float* xs  = (const float*)d_in[0];
    const float* Wx0 = (const float*)d_in[1];
    const float* Wh0 = (const float*)d_in[2];
    const float* b0  = (const float*)d_in[3];
    const float* Wx1 = (const float*)d_in[4];
    const float* Wh1 = (const float*)d_in[5];
    const float* b1  = (const float*)d_in[6];
    float* out = (float*)d_out;

    // Chunk size: two xp buffers + packed weights + states must fit in ws.
    int C = 256;
    while (C > 32) {
        size_t need = 2 * (size_t)BATCH * C * FOURH * 4    // xp0, xp1
                    + 2 * 48000 * 4                        // whp (half2 = 4B)
                    + 2 * (size_t)BATCH * 300 * 4;         // states
        if (need <= ws_size) break;
        C >>= 1;
    }
    char* w = (char*)d_ws;
    float* xp0 = (float*)w;                 w += (size_t)BATCH * C * FOURH * 4;
    float* xp1 = (float*)w;                 w += (size_t)BATCH * C * FOURH * 4;
    half2_t* whp0 = (half2_t*)w;            w += 48000 * 4;
    half2_t* whp1 = (half2_t*)w;            w += 48000 * 4;
    float* st0 = (float*)w;                 w += (size_t)BATCH * 300 * 4;
    float* st1 = (float*)w;

    pack_wh<<<dim3((2 * 48000 + 255) / 256), dim3(256), 0, stream>>>(Wh0, Wh1, whp0);

    const int nchunk = TLEN / C;
    const int gpb = C / 32;  // xproj blocks per batch

    // Software pipeline: slot s runs L0 chunk s and L1 chunk s-1 concurrently.
    // L0 writes its h-sequence into d_out chunk s; slot s+1's L1-xproj reads
    // it, then L1-recur overwrites that chunk with the final output.
    for (int s = 0; s <= nchunk; ++s) {
        const bool hasA = (s < nchunk);   // L0 chunk s
        const bool hasB = (s >= 1);       // L1 chunk s-1
        if (hasA)
            xproj_gemm<<<dim3(BATCH * gpb), dim3(640), 0, stream>>>(
                xs, Wx0, b0, xp0, s * C, C);
        if (hasB)
            xproj_gemm<<<dim3(BATCH * gpb), dim3(640), 0, stream>>>(
                out, Wx1, b1, xp1, (s - 1) * C, C);
        if (hasA && hasB)
            lstm_recur2<<<dim3(128), dim3(768), 0, stream>>>(
                xp0, whp0, st0, s * C, xp1, whp1, st1, (s - 1) * C, out, C);
        else if (hasA)
            lstm_recur2<<<dim3(64), dim3(768), 0, stream>>>(
                xp0, whp0, st0, s * C, xp0, whp0, st0, 0, out, C);
        else
            lstm_recur2<<<dim3(64), dim3(768), 0, stream>>>(
                xp1, whp1, st1, (s - 1) * C, xp1, whp1, st1, 0, out, C);
    }
}

// Round 5
// 2928.099 us; speedup vs baseline: 2.9574x; 1.0213x over previous
//
#include <hip/hip_runtime.h>
#include <cmath>

#define HID 150
#define FOURH 600
#define BATCH 64
#define TLEN 2048
#define NKS 5  // 32-wide k-slices over k padded 150->160

typedef __attribute__((ext_vector_type(2))) _Float16 half2_t;

#if defined(__has_builtin)
#if __has_builtin(__builtin_amdgcn_fdot2)
#define FDOT2(a, b, c) __builtin_amdgcn_fdot2((a), (b), (c), false)
#endif
#endif
#ifndef FDOT2
__device__ __forceinline__ float fdot2_fb(half2_t a, half2_t b, float c) {
    return c + (float)a.x * (float)b.x + (float)a.y * (float)b.y;
}
#define FDOT2(a, b, c) fdot2_fb((a), (b), (c))
#endif

__device__ __forceinline__ float sigmoidf_(float x) {
    return 1.0f / (1.0f + __expf(-x));
}
__device__ __forceinline__ float tanhf_(float x) {
    return 1.0f - 2.0f / (__expf(2.0f * x) + 1.0f);
}

// x_proj[b, i, c] = bias[c] + sum_k X[b, t0+i, k] * Wx[k, c]   (f32)
__global__ __launch_bounds__(640, 2) void xproj_gemm(
    const float* __restrict__ X,     // [BATCH, TLEN, 150]
    const float* __restrict__ Wx,    // [150, 600]
    const float* __restrict__ bias,  // [600]
    float* __restrict__ xp,          // [BATCH, C, 600]
    int t0, int C)
{
    const int blocks_per_batch = C / 32;
    const int b  = blockIdx.x / blocks_per_batch;
    const int i0 = (blockIdx.x % blocks_per_batch) * 32;
    const float* Xbase = X + ((size_t)(b * TLEN + t0 + i0)) * HID;

    __shared__ __align__(16) float xt[150 * 36];
    const int tid = threadIdx.x;
    for (int i = tid; i < 32 * HID; i += 640) {
        int r = i / HID, k = i % HID;
        xt[k * 36 + r] = Xbase[(size_t)r * HID + k];
    }
    __syncthreads();

    if (tid < FOURH) {
        float acc[32];
        #pragma unroll
        for (int r = 0; r < 32; ++r) acc[r] = 0.f;
        for (int k = 0; k < HID; ++k) {
            float w = Wx[(size_t)k * FOURH + tid];
            #pragma unroll
            for (int r4 = 0; r4 < 8; ++r4) {
                float4 xv = *(const float4*)&xt[k * 36 + r4 * 4];
                acc[r4*4+0] += xv.x * w;
                acc[r4*4+1] += xv.y * w;
                acc[r4*4+2] += xv.z * w;
                acc[r4*4+3] += xv.w * w;
            }
        }
        float bv = bias[tid];
        float* o = xp + ((size_t)b * C + i0) * FOURH + tid;
        #pragma unroll
        for (int r = 0; r < 32; ++r) o[(size_t)r * FOURH] = acc[r] + bv;
    }
}

// Pack Wh (f32 [150,600]) into per-thread-sliced half2 layout:
// whp[layer][ks*9600 + (g*16+p)*150 + j] = (Wh[32ks+2p][g*150+j], Wh[32ks+2p+1][...])
__global__ void pack_wh(const float* __restrict__ Wh0, const float* __restrict__ Wh1,
                        half2_t* __restrict__ whp) {
    int idx = blockIdx.x * 256 + threadIdx.x;
    if (idx >= 2 * 48000) return;
    int layer = idx / 48000, r = idx - layer * 48000;
    int j = r % HID, t = r / HID;       // t = (ks*4+g)*16+p
    int p = t & 15, gks = t >> 4;
    int g = gks & 3, ks = gks >> 2;
    const float* Wh = layer ? Wh1 : Wh0;
    int k0 = ks * 32 + 2 * p;
    float a  = (k0 < HID)     ? Wh[(size_t)k0 * FOURH + g * HID + j]       : 0.f;
    float bb = (k0 + 1 < HID) ? Wh[(size_t)(k0 + 1) * FOURH + g * HID + j] : 0.f;
    half2_t h; h.x = (_Float16)a; h.y = (_Float16)bb;
    whp[idx] = h;
}

// ---- literal-index weight machinery ----
#define WL(arr, G, P) arr[(P)] = Wj[((G) * 16 + (P)) * HID];
#define WL16(arr, G) WL(arr,G,0) WL(arr,G,1) WL(arr,G,2) WL(arr,G,3) WL(arr,G,4) \
  WL(arr,G,5) WL(arr,G,6) WL(arr,G,7) WL(arr,G,8) WL(arr,G,9) WL(arr,G,10) \
  WL(arr,G,11) WL(arr,G,12) WL(arr,G,13) WL(arr,G,14) WL(arr,G,15)

// Liveness laundering: opaque VGPR redefinition. LLVM cannot rematerialize
// the value from memory afterwards, so it MUST stay register-resident across
// the recurrence loop (the allocator was re-loading weights every step; see
// round-4 journal: VGPR_Count 56 = remat, not budget).
#define KEEP2(x) do { float _kf = __builtin_bit_cast(float, (x)); \
    asm("" : "+v"(_kf)); (x) = __builtin_bit_cast(half2_t, _kf); } while (0)
#define KEEP4(arr, B) KEEP2(arr[(B)+0]); KEEP2(arr[(B)+1]); KEEP2(arr[(B)+2]); KEEP2(arr[(B)+3]);
#define KEEP16(arr) KEEP4(arr,0) KEEP4(arr,4) KEEP4(arr,8) KEEP4(arr,12)

// One quarter of the k-slice: 4 half2 of h (16B LDS read), 16 fdot2.
#define DOTQ(Q) { \
  float4 hv = *(const float4*)(const void*)&h16[ks * 32 + (Q) * 8]; \
  half2_t h0 = __builtin_bit_cast(half2_t, hv.x); \
  half2_t h1 = __builtin_bit_cast(half2_t, hv.y); \
  half2_t h2 = __builtin_bit_cast(half2_t, hv.z); \
  half2_t h3 = __builtin_bit_cast(half2_t, hv.w); \
  a0 = FDOT2(h0, w0[(Q)*4+0], a0); a0 = FDOT2(h1, w0[(Q)*4+1], a0); \
  a0 = FDOT2(h2, w0[(Q)*4+2], a0); a0 = FDOT2(h3, w0[(Q)*4+3], a0); \
  a1 = FDOT2(h0, w1[(Q)*4+0], a1); a1 = FDOT2(h1, w1[(Q)*4+1], a1); \
  a1 = FDOT2(h2, w1[(Q)*4+2], a1); a1 = FDOT2(h3, w1[(Q)*4+3], a1); \
  a2 = FDOT2(h0, w2[(Q)*4+0], a2); a2 = FDOT2(h1, w2[(Q)*4+1], a2); \
  a2 = FDOT2(h2, w2[(Q)*4+2], a2); a2 = FDOT2(h3, w2[(Q)*4+3], a2); \
  a3 = FDOT2(h0, w3[(Q)*4+0], a3); a3 = FDOT2(h1, w3[(Q)*4+1], a3); \
  a3 = FDOT2(h2, w3[(Q)*4+2], a3); a3 = FDOT2(h3, w3[(Q)*4+3], a3); }

// Dual-part recurrence: WGs 0-63 = part A, WGs 64-127 = part B (other layer,
// previous chunk). 768 threads; thread (j, ks) owns all 4 gates of unit j
// over a 32-wide k-slice as 64 packed half2 registers (asm-pinned).
__global__ __launch_bounds__(768)
__attribute__((amdgpu_waves_per_eu(3, 3)))
void lstm_recur2(const float* __restrict__ xpA, const half2_t* __restrict__ whpA,
                 float* __restrict__ stA, int t0A,
                 const float* __restrict__ xpB, const half2_t* __restrict__ whpB,
                 float* __restrict__ stB, int t0B,
                 float* __restrict__ out, int C)
{
    const int part = blockIdx.x >> 6;
    const int b = blockIdx.x & 63;
    const int tid = threadIdx.x;
    const int tidc = (tid < 750) ? tid : 749;   // clamp: unconditional loads
    const int ks = tidc / HID;       // 0..4
    const int j  = tidc - ks * HID;  // 0..149

    const float*   xp    = part ? xpB  : xpA;
    const half2_t* whp   = part ? whpB : whpA;
    float*         state = part ? stB  : stA;
    const int      t0    = part ? t0B  : t0A;

    __shared__ __align__(16) _Float16 h16[160];      // h as f16, tail zero
    __shared__ __align__(16) float part_s[NKS][4][152];

    half2_t w0[16], w1[16], w2[16], w3[16];
    {
        const half2_t* Wj = whp + (size_t)ks * 9600 + j;
        WL16(w0, 0) WL16(w1, 1) WL16(w2, 2) WL16(w3, 3)
    }
    KEEP16(w0) KEEP16(w1) KEEP16(w2) KEEP16(w3)

    float cst = 0.f;
    if (tid < 160) {
        float hv = 0.f;
        if (t0 != 0 && tid < HID) {
            cst = state[b * 300 + tid];
            hv  = state[b * 300 + HID + tid];
        }
        h16[tid] = (_Float16)hv;
    }
    __syncthreads();

    const float* xpb = xp + (size_t)b * C * FOURH;
    float* outb = out + ((size_t)b * TLEN + t0) * HID;

    float xn0 = 0.f, xn1 = 0.f, xn2 = 0.f, xn3 = 0.f;
    if (tid < HID) {
        xn0 = xpb[tid];
        xn1 = xpb[HID + tid];
        xn2 = xpb[2 * HID + tid];
        xn3 = xpb[3 * HID + tid];
    }

    for (int i = 0; i < C; ++i) {
        // ---- Stage A: 64 v_dot2 per thread (750 threads) ----
        if (tid < 750) {
            float a0 = 0.f, a1 = 0.f, a2 = 0.f, a3 = 0.f;
            DOTQ(0) DOTQ(1) DOTQ(2) DOTQ(3)
            part_s[ks][0][j] = a0;
            part_s[ks][1][j] = a1;
            part_s[ks][2][j] = a2;
            part_s[ks][3][j] = a3;
        }
        __syncthreads();

        // ---- Stage B: reduce, activate, update c/h (150 threads) ----
        if (tid < HID) {
            float p0 = xn0, p1 = xn1, p2 = xn2, p3 = xn3;
            if (i + 1 < C) {
                const float* p = &xpb[(size_t)(i + 1) * FOURH];
                xn0 = p[tid];
                xn1 = p[HID + tid];
                xn2 = p[2 * HID + tid];
                xn3 = p[3 * HID + tid];
            }
            float z0 = p0, z1 = p1, z2 = p2, z3 = p3;
            #pragma unroll
            for (int s = 0; s < NKS; ++s) {
                z0 += part_s[s][0][tid];
                z1 += part_s[s][1][tid];
                z2 += part_s[s][2][tid];
                z3 += part_s[s][3][tid];
            }
            float ig = sigmoidf_(z0);
            float fg = sigmoidf_(z1);
            float gg = tanhf_(z2);
            float og = sigmoidf_(z3);
            cst = fg * cst + ig * gg;
            float hn = og * tanhf_(cst);
            h16[tid] = (_Float16)hn;
            outb[(size_t)i * HID + tid] = hn;
        }
        __syncthreads();
    }

    if (tid < HID) {
        state[b * 300 + tid] = cst;
        state[b * 300 + HID + tid] = (float)h16[tid];
    }
}

extern "C" void kernel_launch(void* const* d_in, const int* in_sizes, int n_in,
                              void* d_out, int out_size, void* d_ws, size_t ws_size,
                              hipStream_t stream) {
    const float* xs  = (const float*)d_in[0];
    const float* Wx0 = (const float*)d_in[1];
    const float* Wh0 = (const float*)d_in[2];
    const float* b0  = (const float*)d_in[3];
    const float* Wx1 = (const float*)d_in[4];
    const float* Wh1 = (const float*)d_in[5];
    const float* b1  = (const float*)d_in[6];
    float* out = (float*)d_out;

    // Chunk size: two xp buffers + packed weights + states must fit in ws.
    int C = 256;
    while (C > 32) {
        size_t need = 2 * (size_t)BATCH * C * FOURH * 4    // xp0, xp1
                    + 2 * 48000 * 4                        // whp (half2 = 4B)
                    + 2 * (size_t)BATCH * 300 * 4;         // states
        if (need <= ws_size) break;
        C >>= 1;
    }
    char* w = (char*)d_ws;
    float* xp0 = (float*)w;                 w += (size_t)BATCH * C * FOURH * 4;
    float* xp1 = (float*)w;                 w += (size_t)BATCH * C * FOURH * 4;
    half2_t* whp0 = (half2_t*)w;            w += 48000 * 4;
    half2_t* whp1 = (half2_t*)w;            w += 48000 * 4;
    float* st0 = (float*)w;                 w += (size_t)BATCH * 300 * 4;
    float* st1 = (float*)w;

    pack_wh<<<dim3((2 * 48000 + 255) / 256), dim3(256), 0, stream>>>(Wh0, Wh1, whp0);

    const int nchunk = TLEN / C;
    const int gpb = C / 32;  // xproj blocks per batch

    // Software pipeline: slot s runs L0 chunk s and L1 chunk s-1 concurrently.
    for (int s = 0; s <= nchunk; ++s) {
        const bool hasA = (s < nchunk);   // L0 chunk s
        const bool hasB = (s >= 1);       // L1 chunk s-1
        if (hasA)
            xproj_gemm<<<dim3(BATCH * gpb), dim3(640), 0, stream>>>(
                xs, Wx0, b0, xp0, s * C, C);
        if (hasB)
            xproj_gemm<<<dim3(BATCH * gpb), dim3(640), 0, stream>>>(
                out, Wx1, b1, xp1, (s - 1) * C, C);
        if (hasA && hasB)
            lstm_recur2<<<dim3(128), dim3(768), 0, stream>>>(
                xp0, whp0, st0, s * C, xp1, whp1, st1, (s - 1) * C, out, C);
        else if (hasA)
            lstm_recur2<<<dim3(64), dim3(768), 0, stream>>>(
                xp0, whp0, st0, s * C, xp0, whp0, st0, 0, out, C);
        else
            lstm_recur2<<<dim3(64), dim3(768), 0, stream>>>(
                xp1, whp1, st1, (s - 1) * C, xp1, whp1, st1, 0, out, C);
    }
}